// Round 1
// baseline (6693.040 us; speedup 1.0000x reference)
//
#include <hip/hip_runtime.h>
#include <stdint.h>

// Global: forbid mul+add contraction so distance arithmetic matches the
// XLA-CPU reference bit-for-bit (argmax / radius-compare are discontinuous).
// MLP math uses explicit fmaf() so it still gets v_fmac.
#pragma clang fp contract(off)

#define NPT   16384
#define BB    8
#define SS    1024
#define KSAMP 32
#define PTOT  (BB*SS*KSAMP)   // 262144
#define R2    0.04f
#define EPSBN 1e-5f

// ws layout in floats
#define OFF_S1 0
#define OFF_Q1 64
#define OFF_S2 128
#define OFF_Q2 192
#define OFF_S3 256
#define OFF_Q3 384
#define WS_W1F 512            // 64*6
#define WS_B1F (512+384)      // 64
#define WS_W2F 960            // 64*64
#define WS_B2F 5056           // 64
#define WS_W3F 5120           // 128*64
#define WS_B3F 13312          // 128
#define WS_FEAT 16384         // 262144*6

// ---------------------------------------------------------------------------
// 1) Farthest point sampling: one block per batch. 256 thr x 64 pts/thread in
//    registers. 1023 serial iterations; exact first-index argmax semantics.
// ---------------------------------------------------------------------------
__global__ __launch_bounds__(256, 1)
void fps_kernel(const float* __restrict__ xyz, float* __restrict__ newxyz) {
  const int b = blockIdx.x;
  const int t = threadIdx.x;
  const int lane = t & 63;
  const int w = t >> 6;
  const float* xb = xyz + (size_t)b * NPT * 3;

  float x[64], y[64], z[64], d[64];
#pragma unroll
  for (int j = 0; j < 64; ++j) {
    int p = j * 256 + t;                 // ascending point index in j
    x[j] = xb[3 * p];
    y[j] = xb[3 * p + 1];
    z[j] = xb[3 * p + 2];
    d[j] = 1e10f;
  }

  __shared__ float sc[3];
  __shared__ float rv[4];
  __shared__ int   ri[4];

  if (t == 0) {
    float gx = xb[0], gy = xb[1], gz = xb[2];
    sc[0] = gx; sc[1] = gy; sc[2] = gz;
    float* o = newxyz + (size_t)b * SS * 3;   // idx[0] = 0
    o[0] = gx; o[1] = gy; o[2] = gz;
  }
  __syncthreads();

  for (int it = 1; it < SS; ++it) {
    float cx = sc[0], cy = sc[1], cz = sc[2];
    float bv = -1.0f; int bi = 0x7fffffff;
#pragma unroll
    for (int j = 0; j < 64; ++j) {
      float dx = x[j] - cx, dy = y[j] - cy, dz = z[j] - cz;
      float d2 = (dx * dx + dy * dy) + dz * dz;   // no fma (contract off)
      float dm = fminf(d[j], d2);
      d[j] = dm;
      if (dm > bv) { bv = dm; bi = j * 256 + t; }  // strict > keeps first
    }
    // wave butterfly argmax, tie -> lower index
#pragma unroll
    for (int off = 32; off >= 1; off >>= 1) {
      float ov = __shfl_xor(bv, off);
      int   oi = __shfl_xor(bi, off);
      if (ov > bv || (ov == bv && oi < bi)) { bv = ov; bi = oi; }
    }
    if (lane == 0) { rv[w] = bv; ri[w] = bi; }
    __syncthreads();
    if (t == 0) {
      float fv = rv[0]; int fi = ri[0];
#pragma unroll
      for (int ww = 1; ww < 4; ++ww) {
        float ov = rv[ww]; int oi = ri[ww];
        if (ov > fv || (ov == fv && oi < fi)) { fv = ov; fi = oi; }
      }
      float gx = xb[3 * fi], gy = xb[3 * fi + 1], gz = xb[3 * fi + 2];
      sc[0] = gx; sc[1] = gy; sc[2] = gz;
      float* o = newxyz + ((size_t)b * SS + it) * 3;
      o[0] = gx; o[1] = gy; o[2] = gz;
    }
    __syncthreads();
  }
}

// ---------------------------------------------------------------------------
// 2) Ball query + gather (fused): one wave per centroid. Ascending-index scan
//    with ballot => first <=32 in-ball indices (matches ref's sort+slice).
//    Writes feat0[c][k][6] = {xyz - center, points}.
// ---------------------------------------------------------------------------
__global__ __launch_bounds__(256, 2)
void ballq_kernel(const float* __restrict__ xyz, const float* __restrict__ pts,
                  const float* __restrict__ newxyz, float* __restrict__ feat) {
  const int lane = threadIdx.x & 63;
  const int c = blockIdx.x * 4 + (threadIdx.x >> 6);  // 0..8191
  const int b = c >> 10;
  const float* xb = xyz + (size_t)b * NPT * 3;
  const float* pb = pts + (size_t)b * NPT * 3;
  const float cx = newxyz[3 * c], cy = newxyz[3 * c + 1], cz = newxyz[3 * c + 2];
  float* fo = feat + (size_t)c * KSAMP * 6;
  const uint64_t ltm = (1ull << lane) - 1ull;

  int cnt = 0, firstp = 0;
  bool haveFirst = false;
  for (int p0 = 0; p0 < NPT && cnt < KSAMP; p0 += 64) {
    int p = p0 + lane;
    float px = xb[3 * p], py = xb[3 * p + 1], pz = xb[3 * p + 2];
    float dx = cx - px, dy = cy - py, dz = cz - pz;
    float sqr = (dx * dx + dy * dy) + dz * dz;     // no fma
    bool in = (sqr <= R2);                          // !(sqr > r^2)
    uint64_t m = __ballot(in);
    if (!haveFirst && m) { firstp = p0 + (__ffsll((unsigned long long)m) - 1); haveFirst = true; }
    int rank = (int)__popcll(m & ltm);
    int slot = cnt + rank;
    if (in && slot < KSAMP) {
      float* o = fo + slot * 6;
      o[0] = px - cx; o[1] = py - cy; o[2] = pz - cz;
      o[3] = pb[3 * p]; o[4] = pb[3 * p + 1]; o[5] = pb[3 * p + 2];
    }
    cnt += (int)__popcll(m);
  }
  if (cnt < KSAMP) {  // pad with first in-ball point (always exists: center)
    int slot = cnt + lane;
    if (slot < KSAMP) {
      float px = xb[3 * firstp], py = xb[3 * firstp + 1], pz = xb[3 * firstp + 2];
      float* o = fo + slot * 6;
      o[0] = px - cx; o[1] = py - cy; o[2] = pz - cz;
      o[3] = pb[3 * firstp]; o[4] = pb[3 * firstp + 1]; o[5] = pb[3 * firstp + 2];
    }
  }
}

// ---------------------------------------------------------------------------
// MLP helpers. Weight indices are wave-uniform -> scalar loads (SGPR FMAs).
// ---------------------------------------------------------------------------
__device__ __forceinline__ void load_f6(const float* __restrict__ feat, int p, float f[6]) {
  const float* fp = feat + (size_t)p * 6;
#pragma unroll
  for (int i = 0; i < 6; ++i) f[i] = fp[i];
}

__device__ __forceinline__ void layer1_folded(const float* __restrict__ w, const float* __restrict__ b,
                                              const float f[6], float h[64]) {
#pragma unroll
  for (int o = 0; o < 64; ++o) {
    float a = b[o];
#pragma unroll
    for (int i = 0; i < 6; ++i) a = fmaf(w[o * 6 + i], f[i], a);
    h[o] = fmaxf(a, 0.0f);
  }
}

__device__ __forceinline__ void layer64_folded(const float* __restrict__ w, const float* __restrict__ b,
                                               const float hin[64], float hout[64]) {
#pragma unroll
  for (int o = 0; o < 64; ++o) {
    float a = b[o];
#pragma unroll
    for (int i = 0; i < 64; ++i) a = fmaf(w[o * 64 + i], hin[i], a);
    hout[o] = fmaxf(a, 0.0f);
  }
}

// block-wide reduction of 64-channel (sum, sumsq) partials into global stats
__device__ __forceinline__ void block_stats_reduce64(float* s, float* q,
                                                     float* __restrict__ gs, float* __restrict__ gq) {
  const int lane = threadIdx.x & 63;
#pragma unroll
  for (int o = 0; o < 64; ++o) {
#pragma unroll
    for (int off = 32; off >= 1; off >>= 1) {
      s[o] += __shfl_xor(s[o], off);
      q[o] += __shfl_xor(q[o], off);
    }
  }
  __shared__ float ls[128];
  if (threadIdx.x < 128) ls[threadIdx.x] = 0.0f;
  __syncthreads();
  if (lane == 0) {
#pragma unroll
    for (int o = 0; o < 64; ++o) {
      atomicAdd(&ls[o], s[o]);
      atomicAdd(&ls[64 + o], q[o]);
    }
  }
  __syncthreads();
  if (threadIdx.x < 64) atomicAdd(&gs[threadIdx.x], ls[threadIdx.x]);
  else if (threadIdx.x < 128) atomicAdd(&gq[threadIdx.x - 64], ls[threadIdx.x]);
}

// 3) stats of layer-1 pre-activations (raw W1,b1)
__global__ __launch_bounds__(256, 1)
void stats1_kernel(const float* __restrict__ feat, const float* __restrict__ w1,
                   const float* __restrict__ b1, float* __restrict__ stats) {
  float s[64], q[64];
#pragma unroll
  for (int o = 0; o < 64; ++o) { s[o] = 0.0f; q[o] = 0.0f; }
  int gid = blockIdx.x * 256 + threadIdx.x;
  for (int p = gid; p < PTOT; p += 256 * 256) {
    float f[6]; load_f6(feat, p, f);
#pragma unroll
    for (int o = 0; o < 64; ++o) {
      float z = b1[o];
#pragma unroll
      for (int i = 0; i < 6; ++i) z = fmaf(w1[o * 6 + i], f[i], z);
      s[o] += z; q[o] = fmaf(z, z, q[o]);
    }
  }
  block_stats_reduce64(s, q, stats + OFF_S1, stats + OFF_Q1);
}

// fold BN(g,be,mu,var) into next affine: wf = a*w, bf = a*(b-mu)+be
__global__ void finalize_kernel(const float* __restrict__ w, const float* __restrict__ bias,
                                const float* __restrict__ g, const float* __restrict__ be,
                                const float* __restrict__ ssum, const float* __restrict__ sq,
                                float* __restrict__ wf, float* __restrict__ bf,
                                int cout, int cin) {
  int o = blockIdx.x * blockDim.x + threadIdx.x;
  if (o >= cout) return;
  const float M = (float)PTOT;
  float mu = ssum[o] / M;
  float var = sq[o] / M - mu * mu;
  float a = g[o] / sqrtf(var + EPSBN);
  bf[o] = fmaf(a, bias[o] - mu, be[o]);
  for (int i = 0; i < cin; ++i) wf[o * cin + i] = a * w[o * cin + i];
}

// 5) stats of layer-2 pre-activations (recompute h1 from feat0, folded L1)
__global__ __launch_bounds__(256, 1)
void stats2_kernel(const float* __restrict__ feat,
                   const float* __restrict__ w1f, const float* __restrict__ b1f,
                   const float* __restrict__ w2, const float* __restrict__ b2,
                   float* __restrict__ stats) {
  float s[64], q[64];
#pragma unroll
  for (int o = 0; o < 64; ++o) { s[o] = 0.0f; q[o] = 0.0f; }
  int gid = blockIdx.x * 256 + threadIdx.x;
  for (int p = gid; p < PTOT; p += 256 * 256) {
    float f[6]; load_f6(feat, p, f);
    float h1[64]; layer1_folded(w1f, b1f, f, h1);
#pragma unroll
    for (int o = 0; o < 64; ++o) {
      float z = b2[o];
#pragma unroll
      for (int i = 0; i < 64; ++i) z = fmaf(w2[o * 64 + i], h1[i], z);
      s[o] += z; q[o] = fmaf(z, z, q[o]);
    }
  }
  block_stats_reduce64(s, q, stats + OFF_S2, stats + OFF_Q2);
}

// 7) stats of layer-3 pre-activations, channel halves (register pressure)
__global__ __launch_bounds__(256, 1)
void stats3_kernel(const float* __restrict__ feat,
                   const float* __restrict__ w1f, const float* __restrict__ b1f,
                   const float* __restrict__ w2f, const float* __restrict__ b2f,
                   const float* __restrict__ w3, const float* __restrict__ b3,
                   float* __restrict__ stats) {
  const int hf = blockIdx.x >> 8;        // grid = 512: 2 halves x 256 blocks
  const int bid = blockIdx.x & 255;
  const float* w3h = w3 + (size_t)hf * 64 * 64;
  const float* b3h = b3 + hf * 64;
  float s[64], q[64];
#pragma unroll
  for (int o = 0; o < 64; ++o) { s[o] = 0.0f; q[o] = 0.0f; }
  int gid = bid * 256 + threadIdx.x;
  for (int p = gid; p < PTOT; p += 256 * 256) {
    float f[6]; load_f6(feat, p, f);
    float h1[64]; layer1_folded(w1f, b1f, f, h1);
    float h2[64]; layer64_folded(w2f, b2f, h1, h2);
#pragma unroll
    for (int o = 0; o < 64; ++o) {
      float z = b3h[o];
#pragma unroll
      for (int i = 0; i < 64; ++i) z = fmaf(w3h[o * 64 + i], h2[i], z);
      s[o] += z; q[o] = fmaf(z, z, q[o]);
    }
  }
  block_stats_reduce64(s, q, stats + OFF_S3 + hf * 64, stats + OFF_Q3 + hf * 64);
}

// 9) final: recompute chain, folded L3 + relu, max over K=32 via shfl, store
__global__ __launch_bounds__(256, 1)
void final_kernel(const float* __restrict__ feat,
                  const float* __restrict__ w1f, const float* __restrict__ b1f,
                  const float* __restrict__ w2f, const float* __restrict__ b2f,
                  const float* __restrict__ w3f, const float* __restrict__ b3f,
                  float* __restrict__ out2) {
  const int hf = blockIdx.x & 1;
  const int bid = blockIdx.x >> 1;
  const int lane = threadIdx.x & 63;
  const float* w3h = w3f + (size_t)hf * 64 * 64;
  const float* b3h = b3f + hf * 64;
  int gid = bid * 256 + threadIdx.x;    // 0..65535, lanes consecutive
  for (int p = gid; p < PTOT; p += 256 * 256) {
    float f[6]; load_f6(feat, p, f);
    float h1[64]; layer1_folded(w1f, b1f, f, h1);
    float h2[64]; layer64_folded(w2f, b2f, h1, h2);
    float v0 = 0.0f, v1 = 0.0f;
#pragma unroll
    for (int o = 0; o < 64; ++o) {
      float z = b3h[o];
#pragma unroll
      for (int i = 0; i < 64; ++i) z = fmaf(w3h[o * 64 + i], h2[i], z);
      z = fmaxf(z, 0.0f);                              // relu
#pragma unroll
      for (int off = 16; off >= 1; off >>= 1)          // max over 32-lane half (K)
        z = fmaxf(z, __shfl_xor(z, off));
      if ((lane & 31) == (o & 31)) { if (o < 32) v0 = z; else v1 = z; }
    }
    int g = p >> 5;                                    // group = (b,s)
    float* dst = out2 + (size_t)g * 128 + hf * 64 + (lane & 31);
    dst[0]  = v0;                                      // channel hf*64 + (lane&31)
    dst[32] = v1;                                      // channel hf*64 + 32 + ...
  }
}

// ---------------------------------------------------------------------------
extern "C" void kernel_launch(void* const* d_in, const int* in_sizes, int n_in,
                              void* d_out, int out_size, void* d_ws, size_t ws_size,
                              hipStream_t stream) {
  const float* xyz = (const float*)d_in[0];
  const float* pts = (const float*)d_in[1];
  const float* w0  = (const float*)d_in[2];
  const float* b0  = (const float*)d_in[3];
  const float* g0  = (const float*)d_in[4];
  const float* be0 = (const float*)d_in[5];
  const float* w1  = (const float*)d_in[6];
  const float* b1  = (const float*)d_in[7];
  const float* g1  = (const float*)d_in[8];
  const float* be1 = (const float*)d_in[9];
  const float* w2  = (const float*)d_in[10];
  const float* b2  = (const float*)d_in[11];
  const float* g2  = (const float*)d_in[12];
  const float* be2 = (const float*)d_in[13];

  float* out  = (float*)d_out;
  float* nxz  = out;                 // (B,S,3) = 24576 floats
  float* out2 = out + BB * SS * 3;   // (B,S,128)

  float* ws    = (float*)d_ws;
  float* stats = ws;                 // 512 floats, must be zeroed every call
  float* w1f   = ws + WS_W1F;
  float* b1f   = ws + WS_B1F;
  float* w2f   = ws + WS_W2F;
  float* b2f   = ws + WS_B2F;
  float* w3f   = ws + WS_W3F;
  float* b3f   = ws + WS_B3F;
  float* feat  = ws + WS_FEAT;       // 262144*6 floats

  hipMemsetAsync(stats, 0, 512 * sizeof(float), stream);

  fps_kernel<<<BB, 256, 0, stream>>>(xyz, nxz);
  ballq_kernel<<<2048, 256, 0, stream>>>(xyz, pts, nxz, feat);

  stats1_kernel<<<256, 256, 0, stream>>>(feat, w0, b0, stats);
  finalize_kernel<<<1, 64, 0, stream>>>(w0, b0, g0, be0, stats + OFF_S1, stats + OFF_Q1,
                                        w1f, b1f, 64, 6);
  stats2_kernel<<<256, 256, 0, stream>>>(feat, w1f, b1f, w1, b1, stats);
  finalize_kernel<<<1, 64, 0, stream>>>(w1, b1, g1, be1, stats + OFF_S2, stats + OFF_Q2,
                                        w2f, b2f, 64, 64);
  stats3_kernel<<<512, 256, 0, stream>>>(feat, w1f, b1f, w2f, b2f, w2, b2, stats);
  finalize_kernel<<<1, 128, 0, stream>>>(w2, b2, g2, be2, stats + OFF_S3, stats + OFF_Q3,
                                         w3f, b3f, 128, 64);
  final_kernel<<<512, 256, 0, stream>>>(feat, w1f, b1f, w2f, b2f, w3f, b3f, out2);
}

// Round 2
// 2961.361 us; speedup vs baseline: 2.2601x; 2.2601x over previous
//
#include <hip/hip_runtime.h>
#include <stdint.h>

// Forbid mul+add contraction: distance arithmetic must match the numpy
// reference bit-for-bit (argmax / radius-compare are discontinuous).
// MLP math uses explicit fmaf() (exact FMA is fine; only ordering matters).
#pragma clang fp contract(off)

#define NPT   16384
#define BB    8
#define SS    1024
#define KSAMP 32
#define PTOT  (BB*SS*KSAMP)   // 262144
#define NGRP  (BB*SS)         // 8192
#define R2    0.04f
#define EPSBN 1e-5f
#define INV_M 3.814697265625e-06f   // 1/262144, exact power of two

// ws layout (floats)
#define OFF_S1 0
#define OFF_Q1 64
#define OFF_S2 128
#define OFF_Q2 192
#define OFF_S3 256    // 128
#define OFF_Q3 384    // 128
#define OFF_A1 512
#define OFF_C1 576
#define OFF_A2 640
#define OFF_C2 704
#define OFF_A3 768    // 128
#define OFF_C3 896    // 128
#define OFF_ZMAX 1024                  // 8192*128 = 1048576
#define OFF_FEAT (1024 + 1048576)      // 6*262144 = 1572864  (total ~10.5 MB)

// ---------------------------------------------------------------------------
// helpers
// ---------------------------------------------------------------------------
__device__ __forceinline__ float wave_sum(float v) {
#pragma unroll
  for (int off = 32; off; off >>= 1) v += __shfl_xor(v, off);
  return v;  // butterfly: all lanes hold identical total
}
__device__ __forceinline__ float half_max(float v) {
#pragma unroll
  for (int off = 16; off; off >>= 1) v = fmaxf(v, __shfl_xor(v, off));
  return v;  // max within each 32-lane half
}

// ---------------------------------------------------------------------------
// 1) Farthest point sampling: one block per batch, 512 thr x 32 pts/thread in
//    registers (~155 VGPR -> 2 waves/SIMD). 1023 serial iterations, exact
//    numpy argmax semantics (first index on ties). Centroid re-fetched by all
//    lanes from the same L2-resident address (no serialized t0 chain).
// ---------------------------------------------------------------------------
__global__ __launch_bounds__(512, 2)
void fps_kernel(const float* __restrict__ xyz, float* __restrict__ newxyz) {
  const int b = blockIdx.x;
  const int t = threadIdx.x;
  const int lane = t & 63;
  const int w = t >> 6;                 // 8 waves
  const float* xb = xyz + (size_t)b * NPT * 3;

  float x[32], y[32], z[32], d[32];
#pragma unroll
  for (int j = 0; j < 32; ++j) {
    int p = j * 512 + t;
    x[j] = xb[3 * p];
    y[j] = xb[3 * p + 1];
    z[j] = xb[3 * p + 2];
    d[j] = 1e10f;
  }

  __shared__ float rv[8];
  __shared__ int   ri[8];

  int fi = 0;                            // current centroid index (uniform)
  if (t == 0) {
    float* o = newxyz + (size_t)b * SS * 3;   // idx[0] = 0
    o[0] = xb[0]; o[1] = xb[1]; o[2] = xb[2];
  }

  for (int it = 1; it < SS; ++it) {
    // all lanes load the centroid (same address -> L1/L2 broadcast)
    float cx = xb[3 * fi], cy = xb[3 * fi + 1], cz = xb[3 * fi + 2];
    float bv = -1.0f; int bi = 0x7fffffff;
#pragma unroll
    for (int j = 0; j < 32; ++j) {
      float dx = x[j] - cx, dy = y[j] - cy, dz = z[j] - cz;
      float d2 = (dx * dx + dy * dy) + dz * dz;   // matches numpy order
      float dm = fminf(d[j], d2);
      d[j] = dm;
      if (dm > bv) { bv = dm; bi = j * 512 + t; } // strict > keeps lowest j
    }
#pragma unroll
    for (int off = 32; off >= 1; off >>= 1) {     // wave argmax, tie->low idx
      float ov = __shfl_xor(bv, off);
      int   oi = __shfl_xor(bi, off);
      if (ov > bv || (ov == bv && oi < bi)) { bv = ov; bi = oi; }
    }
    if (lane == 0) { rv[w] = bv; ri[w] = bi; }
    __syncthreads();
    float fv = rv[0]; fi = ri[0];
#pragma unroll
    for (int ww = 1; ww < 8; ++ww) {
      float ov = rv[ww]; int oi = ri[ww];
      if (ov > fv || (ov == fv && oi < fi)) { fv = ov; fi = oi; }
    }
    if (t == 0) {
      float* o = newxyz + ((size_t)b * SS + it) * 3;
      o[0] = xb[3 * fi]; o[1] = xb[3 * fi + 1]; o[2] = xb[3 * fi + 2];
    }
    __syncthreads();   // protect rv/ri against next iteration's writes
  }
}

// ---------------------------------------------------------------------------
// 2) Ball query + gather (fused): one wave per centroid, ascending-index scan
//    with ballot == ref's sort+slice. feat is channel-major [6][PTOT].
// ---------------------------------------------------------------------------
__global__ __launch_bounds__(256, 2)
void ballq_kernel(const float* __restrict__ xyz, const float* __restrict__ pts,
                  const float* __restrict__ newxyz, float* __restrict__ feat) {
  const int lane = threadIdx.x & 63;
  const int c = blockIdx.x * 4 + (threadIdx.x >> 6);  // 0..8191
  const int b = c >> 10;
  const float* xb = xyz + (size_t)b * NPT * 3;
  const float* pb = pts + (size_t)b * NPT * 3;
  const float cx = newxyz[3 * c], cy = newxyz[3 * c + 1], cz = newxyz[3 * c + 2];
  const int base = c * KSAMP;
  const uint64_t ltm = (1ull << lane) - 1ull;

  int cnt = 0, firstp = 0;
  bool haveFirst = false;
  for (int p0 = 0; p0 < NPT && cnt < KSAMP; p0 += 64) {
    int p = p0 + lane;
    float px = xb[3 * p], py = xb[3 * p + 1], pz = xb[3 * p + 2];
    float dx = cx - px, dy = cy - py, dz = cz - pz;
    float sqr = (dx * dx + dy * dy) + dz * dz;
    bool in = (sqr <= R2);                          // !(sqr > r^2)
    uint64_t m = __ballot(in);
    if (!haveFirst && m) { firstp = p0 + (__ffsll((unsigned long long)m) - 1); haveFirst = true; }
    int rank = (int)__popcll(m & ltm);
    int slot = cnt + rank;
    if (in && slot < KSAMP) {
      int idx = base + slot;
      feat[0 * PTOT + idx] = px - cx;
      feat[1 * PTOT + idx] = py - cy;
      feat[2 * PTOT + idx] = pz - cz;
      feat[3 * PTOT + idx] = pb[3 * p];
      feat[4 * PTOT + idx] = pb[3 * p + 1];
      feat[5 * PTOT + idx] = pb[3 * p + 2];
    }
    cnt += (int)__popcll(m);
  }
  if (cnt < KSAMP) {  // pad with first in-ball point (center itself qualifies)
    int slot = cnt + lane;
    if (slot < KSAMP) {
      int idx = base + slot;
      float px = xb[3 * firstp], py = xb[3 * firstp + 1], pz = xb[3 * firstp + 2];
      feat[0 * PTOT + idx] = px - cx;
      feat[1 * PTOT + idx] = py - cy;
      feat[2 * PTOT + idx] = pz - cz;
      feat[3 * PTOT + idx] = pb[3 * firstp];
      feat[4 * PTOT + idx] = pb[3 * firstp + 1];
      feat[5 * PTOT + idx] = pb[3 * firstp + 2];
    }
  }
}

// ---------------------------------------------------------------------------
// 3) stats of layer-1 pre-activations. Per-thread s[64],q[64] (cheap here:
//    only 6 FMA per channel). Block-reduce -> global atomics.
// ---------------------------------------------------------------------------
__global__ __launch_bounds__(256, 2)
void mlp1s_kernel(const float* __restrict__ feat, const float* __restrict__ w0,
                  const float* __restrict__ b0, float* __restrict__ stats) {
  float s[64], q[64];
#pragma unroll
  for (int o = 0; o < 64; ++o) { s[o] = 0.0f; q[o] = 0.0f; }
  int gid = blockIdx.x * 256 + threadIdx.x;
  for (int p = gid; p < PTOT; p += 256 * 256) {
    float f[6];
#pragma unroll
    for (int ch = 0; ch < 6; ++ch) f[ch] = feat[ch * PTOT + p];
#pragma unroll
    for (int o = 0; o < 64; ++o) {
      float z = b0[o];
#pragma unroll
      for (int i = 0; i < 6; ++i) z = fmaf(w0[o * 6 + i], f[i], z);
      s[o] += z; q[o] = fmaf(z, z, q[o]);
    }
  }
  const int lane = threadIdx.x & 63;
#pragma unroll
  for (int o = 0; o < 64; ++o) { s[o] = wave_sum(s[o]); q[o] = wave_sum(q[o]); }
  __shared__ float ls[128];
  if (threadIdx.x < 128) ls[threadIdx.x] = 0.0f;
  __syncthreads();
  if (lane == 0) {
#pragma unroll
    for (int o = 0; o < 64; ++o) { atomicAdd(&ls[o], s[o]); atomicAdd(&ls[64 + o], q[o]); }
  }
  __syncthreads();
  if (threadIdx.x < 64) atomicAdd(&stats[OFF_S1 + threadIdx.x], ls[threadIdx.x]);
  else if (threadIdx.x < 128) atomicAdd(&stats[OFF_Q1 + threadIdx.x - 64], ls[threadIdx.x]);
}

// ---------------------------------------------------------------------------
// BN fold: a = g/sqrt(var+eps), c = be - a*mu   (h = relu(a*z + c))
// ---------------------------------------------------------------------------
__global__ void fin_kernel(const float* __restrict__ g, const float* __restrict__ be,
                           const float* __restrict__ s, const float* __restrict__ q,
                           float* __restrict__ A, float* __restrict__ C, int Cn) {
  int o = blockIdx.x * blockDim.x + threadIdx.x;
  if (o >= Cn) return;
  float mu = s[o] * INV_M;
  float var = q[o] * INV_M - mu * mu;
  float a = g[o] / sqrtf(var + EPSBN);
  A[o] = a;
  C[o] = be[o] - a * mu;
}

// ---------------------------------------------------------------------------
// 4) stats of layer-2 pre-activations. h1 built explicitly (unrolled o),
//    then rolled-o loop: scalar z2 accumulators + wave-butterfly stats into
//    4 designated-lane registers. ~110 VGPR.
// ---------------------------------------------------------------------------
__global__ __launch_bounds__(256, 2)
void mlp2s_kernel(const float* __restrict__ feat,
                  const float* __restrict__ w0, const float* __restrict__ b0,
                  const float* __restrict__ w1, const float* __restrict__ b1,
                  const float* __restrict__ par, float* __restrict__ stats) {
  const float* a1 = par + OFF_A1;
  const float* c1 = par + OFF_C1;
  const int lane = threadIdx.x & 63;
  float sp = 0.0f, qp = 0.0f;          // this lane's channel (== lane)
  int gid = blockIdx.x * 256 + threadIdx.x;
  for (int p = gid; p < PTOT; p += 512 * 256) {
    float f[6];
#pragma unroll
    for (int ch = 0; ch < 6; ++ch) f[ch] = feat[ch * PTOT + p];
    float h1[64];
#pragma unroll
    for (int o = 0; o < 64; ++o) {
      float z = b0[o];
#pragma unroll
      for (int i = 0; i < 6; ++i) z = fmaf(w0[o * 6 + i], f[i], z);
      h1[o] = fmaxf(fmaf(a1[o], z, c1[o]), 0.0f);
    }
    for (int o = 0; o < 64; o += 2) {   // rolled: scalar temps only
      float z0 = b1[o], z1 = b1[o + 1];
#pragma unroll
      for (int i = 0; i < 64; ++i) {
        z0 = fmaf(w1[o * 64 + i], h1[i], z0);
        z1 = fmaf(w1[(o + 1) * 64 + i], h1[i], z1);
      }
      float s0 = wave_sum(z0), q0 = wave_sum(z0 * z0);
      float s1 = wave_sum(z1), q1 = wave_sum(z1 * z1);
      if (lane == o)     { sp += s0; qp += q0; }
      if (lane == o + 1) { sp += s1; qp += q1; }
    }
  }
  atomicAdd(&stats[OFF_S2 + lane], sp);
  atomicAdd(&stats[OFF_Q2 + lane], qp);
}

// ---------------------------------------------------------------------------
// 5) layer-3 fused: recompute h1 (per-i, no array), accumulate h2[64]
//    (i-rolled, o-unrolled: constant register indices, small code), then
//    rolled-o layer-3 with butterfly stats + half-wave max (lanes 0-31 and
//    32-63 are two consecutive groups). Writes zmax[g][o] (raw pre-BN max,
//    valid because a3>0 makes relu(a*z+c) monotone).
// ---------------------------------------------------------------------------
__global__ __launch_bounds__(256, 2)
void mlp3f_kernel(const float* __restrict__ feat,
                  const float* __restrict__ w0, const float* __restrict__ b0,
                  const float* __restrict__ w1, const float* __restrict__ b1,
                  const float* __restrict__ w2, const float* __restrict__ b2,
                  const float* __restrict__ par, float* __restrict__ stats,
                  float* __restrict__ zmax) {
  const float* a1 = par + OFF_A1;
  const float* c1 = par + OFF_C1;
  const float* a2 = par + OFF_A2;
  const float* c2 = par + OFF_C2;
  const int lane = threadIdx.x & 63;
  float sp0 = 0.0f, qp0 = 0.0f;        // channel lane
  float sp1 = 0.0f, qp1 = 0.0f;        // channel 64+lane
  int gid = blockIdx.x * 256 + threadIdx.x;
  for (int p = gid; p < PTOT; p += 512 * 256) {
    float f[6];
#pragma unroll
    for (int ch = 0; ch < 6; ++ch) f[ch] = feat[ch * PTOT + p];
    float h2[64];
#pragma unroll
    for (int o = 0; o < 64; ++o) h2[o] = b1[o];
    for (int i = 0; i < 64; ++i) {      // rolled; h1[i] recomputed (8 instr)
      float z = b0[i];
#pragma unroll
      for (int ch = 0; ch < 6; ++ch) z = fmaf(w0[i * 6 + ch], f[ch], z);
      float h1i = fmaxf(fmaf(a1[i], z, c1[i]), 0.0f);
#pragma unroll
      for (int o = 0; o < 64; ++o) h2[o] = fmaf(w1[o * 64 + i], h1i, h2[o]);
    }
#pragma unroll
    for (int o = 0; o < 64; ++o) h2[o] = fmaxf(fmaf(a2[o], h2[o], c2[o]), 0.0f);

    const int g = p >> 5;               // this lane's group
    for (int o = 0; o < 128; o += 2) {  // rolled: scalar temps
      float z0 = b2[o], z1 = b2[o + 1];
#pragma unroll
      for (int i = 0; i < 64; ++i) {
        z0 = fmaf(w2[o * 64 + i], h2[i], z0);
        z1 = fmaf(w2[(o + 1) * 64 + i], h2[i], z1);
      }
      float s0 = wave_sum(z0), q0 = wave_sum(z0 * z0);
      float s1 = wave_sum(z1), q1 = wave_sum(z1 * z1);
      if (lane == (o & 63))       { if (o < 64) { sp0 += s0; qp0 += q0; } else { sp1 += s0; qp1 += q0; } }
      if (lane == ((o + 1) & 63)) { if (o < 64) { sp0 += s1; qp0 += q1; } else { sp1 += s1; qp1 += q1; } }
      float m0 = half_max(z0), m1 = half_max(z1);
      if ((lane & 31) == (o & 31))       zmax[g * 128 + o]     = m0;
      if ((lane & 31) == ((o + 1) & 31)) zmax[g * 128 + o + 1] = m1;
    }
  }
  atomicAdd(&stats[OFF_S3 + lane], sp0);
  atomicAdd(&stats[OFF_Q3 + lane], qp0);
  atomicAdd(&stats[OFF_S3 + 64 + lane], sp1);
  atomicAdd(&stats[OFF_Q3 + 64 + lane], qp1);
}

// ---------------------------------------------------------------------------
// 6) epilogue: out2[g][c] = relu(a3[c]*zmax[g][c] + c3[c])
// ---------------------------------------------------------------------------
__global__ __launch_bounds__(256, 4)
void final_out_kernel(const float* __restrict__ zmax, const float* __restrict__ par,
                      float* __restrict__ out2) {
  const float* a3 = par + OFF_A3;
  const float* c3 = par + OFF_C3;
  int idx = blockIdx.x * 256 + threadIdx.x;   // g*128 + c
  int c = idx & 127;
  out2[idx] = fmaxf(fmaf(a3[c], zmax[idx], c3[c]), 0.0f);
}

// ---------------------------------------------------------------------------
extern "C" void kernel_launch(void* const* d_in, const int* in_sizes, int n_in,
                              void* d_out, int out_size, void* d_ws, size_t ws_size,
                              hipStream_t stream) {
  const float* xyz = (const float*)d_in[0];
  const float* pts = (const float*)d_in[1];
  const float* w0  = (const float*)d_in[2];
  const float* b0  = (const float*)d_in[3];
  const float* g0  = (const float*)d_in[4];
  const float* be0 = (const float*)d_in[5];
  const float* w1  = (const float*)d_in[6];
  const float* b1  = (const float*)d_in[7];
  const float* g1  = (const float*)d_in[8];
  const float* be1 = (const float*)d_in[9];
  const float* w2  = (const float*)d_in[10];
  const float* b2  = (const float*)d_in[11];
  const float* g2  = (const float*)d_in[12];
  const float* be2 = (const float*)d_in[13];

  float* out  = (float*)d_out;
  float* nxz  = out;                 // (B,S,3)
  float* out2 = out + BB * SS * 3;   // (B,S,128)

  float* ws    = (float*)d_ws;
  float* stats = ws;                 // 512 floats, zeroed every call
  float* par   = ws;                 // params addressed via OFF_* macros
  float* zmax  = ws + OFF_ZMAX;
  float* feat  = ws + OFF_FEAT;

  hipMemsetAsync(stats, 0, 512 * sizeof(float), stream);

  fps_kernel<<<BB, 512, 0, stream>>>(xyz, nxz);
  ballq_kernel<<<2048, 256, 0, stream>>>(xyz, pts, nxz, feat);

  mlp1s_kernel<<<256, 256, 0, stream>>>(feat, w0, b0, stats);
  fin_kernel<<<1, 64, 0, stream>>>(g0, be0, stats + OFF_S1, stats + OFF_Q1,
                                   par + OFF_A1, par + OFF_C1, 64);
  mlp2s_kernel<<<512, 256, 0, stream>>>(feat, w0, b0, w1, b1, par, stats);
  fin_kernel<<<1, 64, 0, stream>>>(g1, be1, stats + OFF_S2, stats + OFF_Q2,
                                   par + OFF_A2, par + OFF_C2, 64);
  mlp3f_kernel<<<512, 256, 0, stream>>>(feat, w0, b0, w1, b1, w2, b2, par, stats, zmax);
  fin_kernel<<<1, 128, 0, stream>>>(g2, be2, stats + OFF_S3, stats + OFF_Q3,
                                    par + OFF_A3, par + OFF_C3, 128);
  final_out_kernel<<<4096, 256, 0, stream>>>(zmax, par, out2);
}

// Round 3
// 2916.486 us; speedup vs baseline: 2.2949x; 1.0154x over previous
//
#include <hip/hip_runtime.h>
#include <stdint.h>

// Forbid mul+add contraction: distance arithmetic must match the numpy
// reference bit-for-bit (argmax / radius-compare are discontinuous).
// MLP math uses explicit fmaf() (exact FMA is fine; only ordering matters).
#pragma clang fp contract(off)

#define NPT   16384
#define BB    8
#define SS    1024
#define KSAMP 32
#define PTOT  (BB*SS*KSAMP)   // 262144
#define NGRP  (BB*SS)         // 8192
#define R2    0.04f
#define EPSBN 1e-5f
#define INV_M 3.814697265625e-06f   // 1/262144, exact power of two

// ws layout (floats)
#define OFF_S1 0
#define OFF_Q1 64
#define OFF_S2 128
#define OFF_Q2 192
#define OFF_S3 256    // 128
#define OFF_Q3 384    // 128
#define OFF_A1 512
#define OFF_C1 576
#define OFF_A2 640
#define OFF_C2 704
#define OFF_A3 768    // 128
#define OFF_C3 896    // 128
#define OFF_ZMAX 1024                  // 8192*128 = 1048576
#define OFF_FEAT (1024 + 1048576)      // 6*262144 = 1572864  (total ~10.5 MB)

// ---------------------------------------------------------------------------
// helpers
// ---------------------------------------------------------------------------
__device__ __forceinline__ float wave_sum(float v) {
#pragma unroll
  for (int off = 32; off; off >>= 1) v += __shfl_xor(v, off);
  return v;  // butterfly: all lanes hold identical total
}
__device__ __forceinline__ float half_max(float v) {
#pragma unroll
  for (int off = 16; off; off >>= 1) v = fmaxf(v, __shfl_xor(v, off));
  return v;  // max within each 32-lane half
}

// ---------------------------------------------------------------------------
// 1) Farthest point sampling: one block per batch, 512 thr x 32 pts/thread.
//    KEY FIX vs R2: inline-asm pins x/y/z in VGPRs. R2's VGPR_Count=84 proved
//    the compiler rematerialized the coordinate loads inside the 1023-iter
//    loop (192 KB/iter L1 thrash -> 2.34 us/iter). The empty asm is
//    non-duplicable, so loads stay hoisted. 96+32+temps ~ 170 VGPR fits the
//    256 cap of (512,2) -> 2 waves/SIMD.
//    Also: double-buffered argmax slots -> ONE barrier per iteration.
//    Arithmetic order identical to R2 (bit-exact vs numpy, passed 2x).
// ---------------------------------------------------------------------------
__global__ __launch_bounds__(512, 2)
void fps_kernel(const float* __restrict__ xyz, float* __restrict__ newxyz) {
  const int b = blockIdx.x;
  const int t = threadIdx.x;
  const int lane = t & 63;
  const int w = t >> 6;                 // 8 waves
  const float* xb = xyz + (size_t)b * NPT * 3;

  float x[32], y[32], z[32], d[32];
#pragma unroll
  for (int j = 0; j < 32; ++j) {
    int p = j * 512 + t;
    x[j] = xb[3 * p];
    y[j] = xb[3 * p + 1];
    z[j] = xb[3 * p + 2];
    d[j] = 1e10f;
    asm volatile("" : "+v"(x[j]), "+v"(y[j]), "+v"(z[j]));  // pin in VGPRs
  }

  __shared__ float rv[2][8];
  __shared__ int   ri[2][8];

  int fi = 0;                            // current centroid index (uniform)
  if (t == 0) {
    float* o = newxyz + (size_t)b * SS * 3;   // idx[0] = 0
    o[0] = xb[0]; o[1] = xb[1]; o[2] = xb[2];
  }

  for (int it = 1; it < SS; ++it) {
    // all lanes load the centroid (same address -> L1 broadcast)
    float cx = xb[3 * fi], cy = xb[3 * fi + 1], cz = xb[3 * fi + 2];
    float bv = -1.0f; int bi = 0x7fffffff;
#pragma unroll
    for (int j = 0; j < 32; ++j) {
      float dx = x[j] - cx, dy = y[j] - cy, dz = z[j] - cz;
      float d2 = (dx * dx + dy * dy) + dz * dz;   // matches numpy order
      float dm = fminf(d[j], d2);
      d[j] = dm;
      if (dm > bv) { bv = dm; bi = j * 512 + t; } // strict > keeps lowest j
    }
#pragma unroll
    for (int off = 32; off >= 1; off >>= 1) {     // wave argmax, tie->low idx
      float ov = __shfl_xor(bv, off);
      int   oi = __shfl_xor(bi, off);
      if (ov > bv || (ov == bv && oi < bi)) { bv = ov; bi = oi; }
    }
    const int buf = it & 1;
    if (lane == 0) { rv[buf][w] = bv; ri[buf][w] = bi; }
    __syncthreads();
    // single barrier is safe: next iteration writes the OTHER buffer, and
    // the barrier of iteration it+1 orders those writes after these reads.
    float fv = rv[buf][0]; fi = ri[buf][0];
#pragma unroll
    for (int ww = 1; ww < 8; ++ww) {
      float ov = rv[buf][ww]; int oi = ri[buf][ww];
      if (ov > fv || (ov == fv && oi < fi)) { fv = ov; fi = oi; }
    }
    if (t == 0) {
      float* o = newxyz + ((size_t)b * SS + it) * 3;
      o[0] = xb[3 * fi]; o[1] = xb[3 * fi + 1]; o[2] = xb[3 * fi + 2];
    }
  }
}

// ---------------------------------------------------------------------------
// 2) Ball query + gather (fused): one wave per centroid, ascending-index scan
//    with ballot == ref's sort+slice. feat is channel-major [6][PTOT].
// ---------------------------------------------------------------------------
__global__ __launch_bounds__(256, 2)
void ballq_kernel(const float* __restrict__ xyz, const float* __restrict__ pts,
                  const float* __restrict__ newxyz, float* __restrict__ feat) {
  const int lane = threadIdx.x & 63;
  const int c = blockIdx.x * 4 + (threadIdx.x >> 6);  // 0..8191
  const int b = c >> 10;
  const float* xb = xyz + (size_t)b * NPT * 3;
  const float* pb = pts + (size_t)b * NPT * 3;
  const float cx = newxyz[3 * c], cy = newxyz[3 * c + 1], cz = newxyz[3 * c + 2];
  const int base = c * KSAMP;
  const uint64_t ltm = (1ull << lane) - 1ull;

  int cnt = 0, firstp = 0;
  bool haveFirst = false;
  for (int p0 = 0; p0 < NPT && cnt < KSAMP; p0 += 64) {
    int p = p0 + lane;
    float px = xb[3 * p], py = xb[3 * p + 1], pz = xb[3 * p + 2];
    float dx = cx - px, dy = cy - py, dz = cz - pz;
    float sqr = (dx * dx + dy * dy) + dz * dz;
    bool in = (sqr <= R2);                          // !(sqr > r^2)
    uint64_t m = __ballot(in);
    if (!haveFirst && m) { firstp = p0 + (__ffsll((unsigned long long)m) - 1); haveFirst = true; }
    int rank = (int)__popcll(m & ltm);
    int slot = cnt + rank;
    if (in && slot < KSAMP) {
      int idx = base + slot;
      feat[0 * PTOT + idx] = px - cx;
      feat[1 * PTOT + idx] = py - cy;
      feat[2 * PTOT + idx] = pz - cz;
      feat[3 * PTOT + idx] = pb[3 * p];
      feat[4 * PTOT + idx] = pb[3 * p + 1];
      feat[5 * PTOT + idx] = pb[3 * p + 2];
    }
    cnt += (int)__popcll(m);
  }
  if (cnt < KSAMP) {  // pad with first in-ball point (center itself qualifies)
    int slot = cnt + lane;
    if (slot < KSAMP) {
      int idx = base + slot;
      float px = xb[3 * firstp], py = xb[3 * firstp + 1], pz = xb[3 * firstp + 2];
      feat[0 * PTOT + idx] = px - cx;
      feat[1 * PTOT + idx] = py - cy;
      feat[2 * PTOT + idx] = pz - cz;
      feat[3 * PTOT + idx] = pb[3 * firstp];
      feat[4 * PTOT + idx] = pb[3 * firstp + 1];
      feat[5 * PTOT + idx] = pb[3 * firstp + 2];
    }
  }
}

// ---------------------------------------------------------------------------
// 3) stats of layer-1 pre-activations. Per-thread s[64],q[64] (cheap here:
//    only 6 FMA per channel). Block-reduce -> global atomics.
// ---------------------------------------------------------------------------
__global__ __launch_bounds__(256, 2)
void mlp1s_kernel(const float* __restrict__ feat, const float* __restrict__ w0,
                  const float* __restrict__ b0, float* __restrict__ stats) {
  float s[64], q[64];
#pragma unroll
  for (int o = 0; o < 64; ++o) { s[o] = 0.0f; q[o] = 0.0f; }
  int gid = blockIdx.x * 256 + threadIdx.x;
  for (int p = gid; p < PTOT; p += 256 * 256) {
    float f[6];
#pragma unroll
    for (int ch = 0; ch < 6; ++ch) f[ch] = feat[ch * PTOT + p];
#pragma unroll
    for (int o = 0; o < 64; ++o) {
      float z = b0[o];
#pragma unroll
      for (int i = 0; i < 6; ++i) z = fmaf(w0[o * 6 + i], f[i], z);
      s[o] += z; q[o] = fmaf(z, z, q[o]);
    }
  }
  const int lane = threadIdx.x & 63;
#pragma unroll
  for (int o = 0; o < 64; ++o) { s[o] = wave_sum(s[o]); q[o] = wave_sum(q[o]); }
  __shared__ float ls[128];
  if (threadIdx.x < 128) ls[threadIdx.x] = 0.0f;
  __syncthreads();
  if (lane == 0) {
#pragma unroll
    for (int o = 0; o < 64; ++o) { atomicAdd(&ls[o], s[o]); atomicAdd(&ls[64 + o], q[o]); }
  }
  __syncthreads();
  if (threadIdx.x < 64) atomicAdd(&stats[OFF_S1 + threadIdx.x], ls[threadIdx.x]);
  else if (threadIdx.x < 128) atomicAdd(&stats[OFF_Q1 + threadIdx.x - 64], ls[threadIdx.x]);
}

// ---------------------------------------------------------------------------
// BN fold: a = g/sqrt(var+eps), c = be - a*mu   (h = relu(a*z + c))
// ---------------------------------------------------------------------------
__global__ void fin_kernel(const float* __restrict__ g, const float* __restrict__ be,
                           const float* __restrict__ s, const float* __restrict__ q,
                           float* __restrict__ A, float* __restrict__ C, int Cn) {
  int o = blockIdx.x * blockDim.x + threadIdx.x;
  if (o >= Cn) return;
  float mu = s[o] * INV_M;
  float var = q[o] * INV_M - mu * mu;
  float a = g[o] / sqrtf(var + EPSBN);
  A[o] = a;
  C[o] = be[o] - a * mu;
}

// ---------------------------------------------------------------------------
// 4) stats of layer-2 pre-activations. h1 built explicitly (unrolled o),
//    then rolled-o loop: scalar z2 accumulators + wave-butterfly stats into
//    designated-lane registers.
// ---------------------------------------------------------------------------
__global__ __launch_bounds__(256, 2)
void mlp2s_kernel(const float* __restrict__ feat,
                  const float* __restrict__ w0, const float* __restrict__ b0,
                  const float* __restrict__ w1, const float* __restrict__ b1,
                  const float* __restrict__ par, float* __restrict__ stats) {
  const float* a1 = par + OFF_A1;
  const float* c1 = par + OFF_C1;
  const int lane = threadIdx.x & 63;
  float sp = 0.0f, qp = 0.0f;          // this lane's channel (== lane)
  int gid = blockIdx.x * 256 + threadIdx.x;
  for (int p = gid; p < PTOT; p += 512 * 256) {
    float f[6];
#pragma unroll
    for (int ch = 0; ch < 6; ++ch) f[ch] = feat[ch * PTOT + p];
    float h1[64];
#pragma unroll
    for (int o = 0; o < 64; ++o) {
      float z = b0[o];
#pragma unroll
      for (int i = 0; i < 6; ++i) z = fmaf(w0[o * 6 + i], f[i], z);
      h1[o] = fmaxf(fmaf(a1[o], z, c1[o]), 0.0f);
    }
    for (int o = 0; o < 64; o += 2) {   // rolled: scalar temps only
      float z0 = b1[o], z1 = b1[o + 1];
#pragma unroll
      for (int i = 0; i < 64; ++i) {
        z0 = fmaf(w1[o * 64 + i], h1[i], z0);
        z1 = fmaf(w1[(o + 1) * 64 + i], h1[i], z1);
      }
      float s0 = wave_sum(z0), q0 = wave_sum(z0 * z0);
      float s1 = wave_sum(z1), q1 = wave_sum(z1 * z1);
      if (lane == o)     { sp += s0; qp += q0; }
      if (lane == o + 1) { sp += s1; qp += q1; }
    }
  }
  atomicAdd(&stats[OFF_S2 + lane], sp);
  atomicAdd(&stats[OFF_Q2 + lane], qp);
}

// ---------------------------------------------------------------------------
// 5) layer-3 fused: recompute h1 (per-i, no array), accumulate h2[64]
//    (i-rolled, o-unrolled), then rolled-o layer-3 with butterfly stats +
//    half-wave max. Writes zmax[g][o] (raw pre-BN max; valid because a3>0
//    makes relu(a*z+c) monotone).
// ---------------------------------------------------------------------------
__global__ __launch_bounds__(256, 2)
void mlp3f_kernel(const float* __restrict__ feat,
                  const float* __restrict__ w0, const float* __restrict__ b0,
                  const float* __restrict__ w1, const float* __restrict__ b1,
                  const float* __restrict__ w2, const float* __restrict__ b2,
                  const float* __restrict__ par, float* __restrict__ stats,
                  float* __restrict__ zmax) {
  const float* a1 = par + OFF_A1;
  const float* c1 = par + OFF_C1;
  const float* a2 = par + OFF_A2;
  const float* c2 = par + OFF_C2;
  const int lane = threadIdx.x & 63;
  float sp0 = 0.0f, qp0 = 0.0f;        // channel lane
  float sp1 = 0.0f, qp1 = 0.0f;        // channel 64+lane
  int gid = blockIdx.x * 256 + threadIdx.x;
  for (int p = gid; p < PTOT; p += 512 * 256) {
    float f[6];
#pragma unroll
    for (int ch = 0; ch < 6; ++ch) f[ch] = feat[ch * PTOT + p];
    float h2[64];
#pragma unroll
    for (int o = 0; o < 64; ++o) h2[o] = b1[o];
    for (int i = 0; i < 64; ++i) {      // rolled; h1[i] recomputed (8 instr)
      float z = b0[i];
#pragma unroll
      for (int ch = 0; ch < 6; ++ch) z = fmaf(w0[i * 6 + ch], f[ch], z);
      float h1i = fmaxf(fmaf(a1[i], z, c1[i]), 0.0f);
#pragma unroll
      for (int o = 0; o < 64; ++o) h2[o] = fmaf(w1[o * 64 + i], h1i, h2[o]);
    }
#pragma unroll
    for (int o = 0; o < 64; ++o) h2[o] = fmaxf(fmaf(a2[o], h2[o], c2[o]), 0.0f);

    const int g = p >> 5;               // this lane's group
    for (int o = 0; o < 128; o += 2) {  // rolled: scalar temps
      float z0 = b2[o], z1 = b2[o + 1];
#pragma unroll
      for (int i = 0; i < 64; ++i) {
        z0 = fmaf(w2[o * 64 + i], h2[i], z0);
        z1 = fmaf(w2[(o + 1) * 64 + i], h2[i], z1);
      }
      float s0 = wave_sum(z0), q0 = wave_sum(z0 * z0);
      float s1 = wave_sum(z1), q1 = wave_sum(z1 * z1);
      if (lane == (o & 63))       { if (o < 64) { sp0 += s0; qp0 += q0; } else { sp1 += s0; qp1 += q0; } }
      if (lane == ((o + 1) & 63)) { if (o < 64) { sp0 += s1; qp0 += q1; } else { sp1 += s1; qp1 += q1; } }
      float m0 = half_max(z0), m1 = half_max(z1);
      if ((lane & 31) == (o & 31))       zmax[g * 128 + o]     = m0;
      if ((lane & 31) == ((o + 1) & 31)) zmax[g * 128 + o + 1] = m1;
    }
  }
  atomicAdd(&stats[OFF_S3 + lane], sp0);
  atomicAdd(&stats[OFF_Q3 + lane], qp0);
  atomicAdd(&stats[OFF_S3 + 64 + lane], sp1);
  atomicAdd(&stats[OFF_Q3 + 64 + lane], qp1);
}

// ---------------------------------------------------------------------------
// 6) epilogue: out2[g][c] = relu(a3[c]*zmax[g][c] + c3[c])
// ---------------------------------------------------------------------------
__global__ __launch_bounds__(256, 4)
void final_out_kernel(const float* __restrict__ zmax, const float* __restrict__ par,
                      float* __restrict__ out2) {
  const float* a3 = par + OFF_A3;
  const float* c3 = par + OFF_C3;
  int idx = blockIdx.x * 256 + threadIdx.x;   // g*128 + c
  int c = idx & 127;
  out2[idx] = fmaxf(fmaf(a3[c], zmax[idx], c3[c]), 0.0f);
}

// ---------------------------------------------------------------------------
extern "C" void kernel_launch(void* const* d_in, const int* in_sizes, int n_in,
                              void* d_out, int out_size, void* d_ws, size_t ws_size,
                              hipStream_t stream) {
  const float* xyz = (const float*)d_in[0];
  const float* pts = (const float*)d_in[1];
  const float* w0  = (const float*)d_in[2];
  const float* b0  = (const float*)d_in[3];
  const float* g0  = (const float*)d_in[4];
  const float* be0 = (const float*)d_in[5];
  const float* w1  = (const float*)d_in[6];
  const float* b1  = (const float*)d_in[7];
  const float* g1  = (const float*)d_in[8];
  const float* be1 = (const float*)d_in[9];
  const float* w2  = (const float*)d_in[10];
  const float* b2  = (const float*)d_in[11];
  const float* g2  = (const float*)d_in[12];
  const float* be2 = (const float*)d_in[13];

  float* out  = (float*)d_out;
  float* nxz  = out;                 // (B,S,3)
  float* out2 = out + BB * SS * 3;   // (B,S,128)

  float* ws    = (float*)d_ws;
  float* stats = ws;                 // 512 floats, zeroed every call
  float* par   = ws;                 // params addressed via OFF_* macros
  float* zmax  = ws + OFF_ZMAX;
  float* feat  = ws + OFF_FEAT;

  hipMemsetAsync(stats, 0, 512 * sizeof(float), stream);

  fps_kernel<<<BB, 512, 0, stream>>>(xyz, nxz);
  ballq_kernel<<<2048, 256, 0, stream>>>(xyz, pts, nxz, feat);

  mlp1s_kernel<<<256, 256, 0, stream>>>(feat, w0, b0, stats);
  fin_kernel<<<1, 64, 0, stream>>>(g0, be0, stats + OFF_S1, stats + OFF_Q1,
                                   par + OFF_A1, par + OFF_C1, 64);
  mlp2s_kernel<<<512, 256, 0, stream>>>(feat, w0, b0, w1, b1, par, stats);
  fin_kernel<<<1, 64, 0, stream>>>(g1, be1, stats + OFF_S2, stats + OFF_Q2,
                                   par + OFF_A2, par + OFF_C2, 64);
  mlp3f_kernel<<<512, 256, 0, stream>>>(feat, w0, b0, w1, b1, w2, b2, par, stats, zmax);
  fin_kernel<<<1, 128, 0, stream>>>(g2, be2, stats + OFF_S3, stats + OFF_Q3,
                                    par + OFF_A3, par + OFF_C3, 128);
  final_out_kernel<<<4096, 256, 0, stream>>>(zmax, par, out2);
}